// Round 14
// baseline (67.430 us; speedup 1.0000x reference)
//
#include <hip/hip_runtime.h>
#include <hip/hip_bf16.h>

#define BB 4
#define NN 2048
#define FIN 128
#define NH 4
#define DH 32
#define NS 0.2f
#define JP 2

typedef unsigned int u32;
typedef unsigned short u16;
typedef unsigned long long u64;
typedef __attribute__((ext_vector_type(8))) short short8;
typedef __attribute__((ext_vector_type(4))) float f32x4;
typedef __attribute__((ext_vector_type(4))) unsigned int u32x4;

// ws float offsets
#define OFF_ES   0         // [16][2048] f32
#define OFF_PQ   32768     // [16][2048] u32 (bf16 Q hi | bf16 P lo)
#define OFF_HT   65536     // u16 [16][32][2048] = 1048576 u16 = 524288 floats
#define OFF_BITS 589824    // u32 [4][2048][64] = 524288 u32
#define OFF_PACC 1114112   // f32 [JP][16][2048][32] = 2097152
#define OFF_PS   3211264   // f32 [JP][16][2048]     = 65536
#define PACC_STRIDE ((size_t)16 * NN * 32)
#define PS_STRIDE   ((size_t)16 * NN)

__device__ __forceinline__ u16 f2bf_rne(float f) {
  unsigned u = __float_as_uint(f);
  return (u16)((u + 0x7fffu + ((u >> 16) & 1u)) >> 16);
}

__device__ __forceinline__ int bitmask(u32 w, int e) {
#if __has_builtin(__builtin_amdgcn_sbfe)
  return __builtin_amdgcn_sbfe((int)w, e, 1);     // v_bfe_i32: 0 or -1
#else
  return ((int)(w << (31 - e))) >> 31;
#endif
}

// ---------------- K0: pack adj -> bitmask (0 LDS, full occupancy) -----------
__global__ __launch_bounds__(256) void k_pack(const int* __restrict__ adj,
                                              u32* __restrict__ bits) {
  const int row = (blockIdx.x << 2) | (threadIdx.x >> 6);  // b*2048+i
  const int lane = threadIdx.x & 63;
  const int* src = adj + (size_t)row * NN;
  u32* dst = bits + (size_t)row * 64;
#pragma unroll 8
  for (int it = 0; it < 32; ++it) {
    const int v = src[it * 64 + lane];
    const u64 m = __ballot(v != 0);
    if (lane == 0) *(u64*)(dst + it * 2) = m;
  }
}

// ---------------- K1: projection + e_src + P/Q tables + bf16 hT -------------
// No max-shift needed: softmax quotient is shift-invariant and unshifted
// exp args are bounded (~e^9) well inside fp32/bf16 range.
__global__ __launch_bounds__(256) void k_proj(
    const float* __restrict__ x, const float* __restrict__ W,
    const float* __restrict__ a, u16* __restrict__ hT,
    float* __restrict__ e_src, u32* __restrict__ PQ) {
  __shared__ float Ws[FIN * 128];
  const int tid = threadIdx.x;
  const int f = tid & 127, g = tid >> 7;
  const float4* Wg4 = (const float4*)W;
  float4* Ws4 = (float4*)Ws;
#pragma unroll
  for (int t = 0; t < 16; ++t) Ws4[t * 256 + tid] = Wg4[t * 256 + tid];
  __syncthreads();

  const int rb = blockIdx.x * 16 + g * 8;
  const int head = f >> 5, d = f & 31;
  const int b = rb >> 11, n0 = rb & (NN - 1);
  const int bh = b * NH + head;
  const float a_s = a[head * (2 * DH) + d];
  const float a_d = a[head * (2 * DH) + DH + d];

  float acc[8];
#pragma unroll
  for (int r = 0; r < 8; ++r) acc[r] = 0.f;

  const float* xb = x + (size_t)rb * FIN;  // wave-uniform -> s_loads
  for (int k = 0; k < FIN; ++k) {
    const float wv = Ws[k * 128 + f];
#pragma unroll
    for (int r = 0; r < 8; ++r) acc[r] = fmaf(wv, xb[r * FIN + k], acc[r]);
  }

  u16 hs[8];
#pragma unroll
  for (int r = 0; r < 8; ++r) hs[r] = f2bf_rne(acc[r]);
  u16* dst = hT + ((size_t)bh * DH + d) * NN + n0;
  *(int4*)dst = *(int4*)&hs[0];

#pragma unroll
  for (int r = 0; r < 8; ++r) {
    float s1 = acc[r] * a_s;
    float s2 = acc[r] * a_d;
#pragma unroll
    for (int off = 16; off >= 1; off >>= 1) {
      s1 += __shfl_xor(s1, off);
      s2 += __shfl_xor(s2, off);
    }
    if (d == 0) {
      e_src[(size_t)bh * NN + n0 + r] = s1;
      const u32 pb = f2bf_rne(__expf(s2));        // P = exp(e_dst)
      const u32 qb = f2bf_rne(__expf(NS * s2));   // Q = exp(0.2 e_dst)
      PQ[(size_t)bh * NN + n0 + r] = (qb << 16) | pb;
    }
  }
}

// ---------------- K2: j-split masked-softmax MFMA aggregation ---------------
// JP=2 partitions -> grid 2048 (8 blocks/CU target, ~6 waves/SIMD VGPR-capped).
// 32 rows/block, 4 waves = 4 j-sub-quarters of this partition. Direct hT
// loads (no LDS staging -> low VGPR), bits hoisted, PQ point-of-use,
// denominators on the matrix pipe. Partial outputs -> pacc/pS.
__global__ __launch_bounds__(256) void k_attn(
    const u16* __restrict__ hT, const float* __restrict__ e_src,
    const u32* __restrict__ PQv, const u32* __restrict__ bits,
    float* __restrict__ pacc, float* __restrict__ pS) {
  __shared__ float part[4][32][33];
  __shared__ float sp[4][2][16];

  const int bid = blockIdx.x;          // jp*1024 + bh*64 + it
  const int jp = bid >> 10;
  const int bh = (bid >> 6) & 15;
  const int it = bid & 63;
  const int b = bh >> 2;

  const int w = threadIdx.x >> 6;
  const int lane = threadIdx.x & 63;
  const int lg = lane >> 4, lm = lane & 15;

  const int i0 = it * 32 + lm;
  const int i1 = i0 + 16;
  const float es0 = e_src[(size_t)bh * NN + i0];
  const float es1 = e_src[(size_t)bh * NN + i1];
  const float A0 = __expf(es0), B0 = __expf(NS * es0);
  const float A1 = __expf(es1), B1 = __expf(NS * es1);
  // w = exp(lrelu(es+ed)) = max(A*P_j, B*Q_j)   (exp monotone, exact)

  const int jwbase = jp * 1024 + w * 256;        // this wave's 256-j window
  const u32* PQb = PQv + (size_t)bh * NN + jwbase;
  const u16* hb0 = hT + ((size_t)bh * DH + lm) * NN + jwbase;
  const u16* hb1 = hT + ((size_t)bh * DH + 16 + lm) * NN + jwbase;
  const int wbase = jwbase >> 5;                 // bits word index base
  const u32* br0 = bits + ((size_t)b * NN + i0) * 64 + wbase;
  const u32* br1 = bits + ((size_t)b * NN + i1) * 64 + wbase;
  const int shamt = lg * 8;
  const int jb = lg * 8;

  // hoist this wave's 8 bit-words per row (2 x int4 per row)
  u32 wd0[8], wd1[8];
#pragma unroll
  for (int q = 0; q < 2; ++q) {
    const u32x4 v0 = *(const u32x4*)(br0 + q * 4);
    const u32x4 v1 = *(const u32x4*)(br1 + q * 4);
#pragma unroll
    for (int k2 = 0; k2 < 4; ++k2) { wd0[q * 4 + k2] = v0[k2]; wd1[q * 4 + k2] = v1[k2]; }
  }

  short8 ones;
#pragma unroll
  for (int e = 0; e < 8; ++e) ones[e] = (short)0x3F80;  // bf16 1.0

  f32x4 acc00 = {0,0,0,0}, acc01 = {0,0,0,0};
  f32x4 acc10 = {0,0,0,0}, acc11 = {0,0,0,0};
  f32x4 accS0 = {0,0,0,0}, accS1 = {0,0,0,0};

#pragma unroll
  for (int t = 0; t < 8; ++t) {        // 8 chunks x 32 j
    const int jj = t * 32 + jb;
    const u32x4 pqa = *(const u32x4*)(PQb + jj);
    const u32x4 pqb = *(const u32x4*)(PQb + jj + 4);
    const short8 hv0 = *(const short8*)(hb0 + jj);
    const short8 hv1 = *(const short8*)(hb1 + jj);
    const u32 wsh0 = wd0[t] >> shamt;  // static index (unrolled)
    const u32 wsh1 = wd1[t] >> shamt;
    short8 af0, af1;
#pragma unroll
    for (int e = 0; e < 8; ++e) {
      const u32 pq = (e < 4) ? pqa[e] : pqb[e - 4];
      const float Pf = __uint_as_float(pq << 16);
      const float Qf = __uint_as_float(pq & 0xffff0000u);
      const int m0 = bitmask(wsh0, e);
      const int m1 = bitmask(wsh1, e);
      float w0 = fmaxf(A0 * Pf, B0 * Qf);
      w0 = __int_as_float(__float_as_int(w0) & m0);
      af0[e] = (short)__builtin_bit_cast(unsigned short, __float2bfloat16(w0));
      float w1 = fmaxf(A1 * Pf, B1 * Qf);
      w1 = __int_as_float(__float_as_int(w1) & m1);
      af1[e] = (short)__builtin_bit_cast(unsigned short, __float2bfloat16(w1));
    }
    __builtin_amdgcn_s_setprio(1);
    acc00 = __builtin_amdgcn_mfma_f32_16x16x32_bf16(af0, hv0, acc00, 0, 0, 0);
    acc01 = __builtin_amdgcn_mfma_f32_16x16x32_bf16(af0, hv1, acc01, 0, 0, 0);
    acc10 = __builtin_amdgcn_mfma_f32_16x16x32_bf16(af1, hv0, acc10, 0, 0, 0);
    acc11 = __builtin_amdgcn_mfma_f32_16x16x32_bf16(af1, hv1, acc11, 0, 0, 0);
    accS0 = __builtin_amdgcn_mfma_f32_16x16x32_bf16(af0, ones, accS0, 0, 0, 0);
    accS1 = __builtin_amdgcn_mfma_f32_16x16x32_bf16(af1, ones, accS1, 0, 0, 0);
    __builtin_amdgcn_s_setprio(0);
  }

#pragma unroll
  for (int r = 0; r < 4; ++r) {
    const int rl = lg * 4 + r;   // C row = (lane>>4)*4 + reg
    part[w][rl][lm] = acc00[r];
    part[w][rl][16 + lm] = acc01[r];
    part[w][16 + rl][lm] = acc10[r];
    part[w][16 + rl][16 + lm] = acc11[r];
  }
  if (lm == 0) {
#pragma unroll
    for (int r = 0; r < 4; ++r) {
      sp[w][0][lg * 4 + r] = accS0[r];  // every col holds the row-sum
      sp[w][1][lg * 4 + r] = accS1[r];
    }
  }
  __syncthreads();

  // partial for this jp partition: sum the 4 waves, write pacc/pS
  float* pa = pacc + ((size_t)jp * 16 + bh) * NN * 32;
  float* ps = pS + ((size_t)jp * 16 + bh) * NN;
  const int tid = threadIdx.x;
#pragma unroll
  for (int t = 0; t < 4; ++t) {
    const int idx = t * 256 + tid;
    const int row = idx >> 5, d = idx & 31;
    const float v = part[0][row][d] + part[1][row][d] +
                    part[2][row][d] + part[3][row][d];
    pa[(size_t)(it * 32 + row) * 32 + d] = v;
    if (d == 0) {
      const float s = sp[0][row >> 4][row & 15] + sp[1][row >> 4][row & 15] +
                      sp[2][row >> 4][row & 15] + sp[3][row >> 4][row & 15];
      ps[it * 32 + row] = s;
    }
  }
}

// ---------------- K3: combine JP partitions + elu ---------------------------
__global__ __launch_bounds__(256) void k_comb(
    const float* __restrict__ pacc, const float* __restrict__ pS,
    float* __restrict__ out) {
  const int idx = blockIdx.x * 256 + threadIdx.x;  // < B*N*128
  const int f = idx & 127;
  const int g = idx >> 7;
  const int b = g >> 11, n = g & (NN - 1);
  const int head = f >> 5, d = f & 31;
  const int bh = b * NH + head;
  const size_t base = ((size_t)bh * NN + n) * 32 + d;
  const size_t sbase = (size_t)bh * NN + n;
  float v = 0.f, s = 0.f;
#pragma unroll
  for (int p = 0; p < JP; ++p) {
    v += pacc[(size_t)p * PACC_STRIDE + base];
    s += pS[(size_t)p * PS_STRIDE + sbase];
  }
  const float o = v / s;
  out[idx] = o > 0.f ? o : (__expf(o) - 1.f);
}

extern "C" void kernel_launch(void* const* d_in, const int* in_sizes, int n_in,
                              void* d_out, int out_size, void* d_ws, size_t ws_size,
                              hipStream_t stream) {
  const float* x = (const float*)d_in[0];
  const int* adj = (const int*)d_in[1];
  const float* W = (const float*)d_in[2];
  const float* a = (const float*)d_in[3];
  float* out = (float*)d_out;
  float* ws = (float*)d_ws;

  float* e_src = ws + OFF_ES;
  u32* PQv = (u32*)(ws + OFF_PQ);
  u16* hT = (u16*)(ws + OFF_HT);
  u32* bits = (u32*)(ws + OFF_BITS);
  float* pacc = ws + OFF_PACC;
  float* pS = ws + OFF_PS;

  k_pack<<<(BB * NN) / 4, 256, 0, stream>>>(adj, bits);
  k_proj<<<(BB * NN) / 16, 256, 0, stream>>>(x, W, a, hT, e_src, PQv);
  k_attn<<<JP * BB * NH * 64, 256, 0, stream>>>(hT, e_src, PQv, bits, pacc, pS);
  k_comb<<<(BB * NN * 128) / 256, 256, 0, stream>>>(pacc, pS, out);
}